// Round 11
// baseline (100.209 us; speedup 1.0000x reference)
//
#include <hip/hip_runtime.h>

#define B_   16
#define S_   128
#define R_   1024
#define KIN  25
#define H_   128
#define MID  256
#define KP   160     // weight K stride (5 slabs of 32)

typedef _Float16 h8 __attribute__((ext_vector_type(8)));
typedef _Float16 h2 __attribute__((ext_vector_type(2)));
typedef float    f4v __attribute__((ext_vector_type(4)));

__device__ __forceinline__ h2 pk2(float a, float b) {
    auto r = __builtin_amdgcn_cvt_pkrtz(a, b);
    h2 o; o[0] = (_Float16)r[0]; o[1] = (_Float16)r[1]; return o;
}
__device__ __forceinline__ unsigned h2u(h2 v) {
    union { h2 h; unsigned u; } c; c.h = v; return c.u;
}
__device__ __forceinline__ h8 mk8(unsigned a, unsigned b, unsigned c, unsigned d) {
    union { h8 v; unsigned u[4]; } r; r.u[0] = a; r.u[1] = b; r.u[2] = c; r.u[3] = d;
    return r.v;
}

// inter k-order: [h(0..127) | x(128..152) | c(153) | pad(154..159)]
__device__ __forceinline__ int orig_k(int kp) {
    if (kp < H_)        return KIN + kp;
    if (kp < H_ + KIN)  return kp - H_;
    if (kp == H_ + KIN) return H_ + KIN;
    return -1;
}

// ---------------------------------------------------------------------------
__global__ void prep_kernel(const float* __restrict__ Wo1, const float* __restrict__ Wo2,
                            const float* __restrict__ Wh1, const float* __restrict__ Wh2,
                            _Float16* __restrict__ WTP, _Float16* __restrict__ woP)
{
    const int kp = blockIdx.x;
    const int t  = threadIdx.x;            // 128 threads
    if (kp < KP) {
        const int ok = orig_k(kp);
        float acc = 0.f;
        if (ok >= 0) {
            const float* w1 = Wh1 + (long)ok * MID;
            for (int m = 0; m < MID; ++m)
                acc += w1[m] * Wh2[m * H_ + t];
        }
        WTP[t * KP + kp] = (_Float16)acc;
    } else {
#pragma unroll
        for (int r = 0; r < 2; ++r) {
            int k2 = t + r * 128;
            if (k2 < KP) {
                int ok = orig_k(k2);
                float acc = 0.f;
                if (ok >= 0)
                    for (int m = 0; m < MID; ++m)
                        acc += Wo1[ok * MID + m] * Wo2[m];
                woP[k2] = (_Float16)acc;
            }
        }
    }
}

// ---------------------------------------------------------------------------
// 1024 blocks x 64 thr (1 wave/SIMD, full chip). Wave owns a 16-row chain.
// Recurrence 100% in registers (MFMA D -> pk2 -> permlane32/16_swap -> B-frag).
// 40 MFMAs/step, x-slab issued FIRST (tail-overlap window). out on VALU
// pk-fp16 chains, shfl-reduced in batches of 4 steps. No LDS/barriers in loop.
// ---------------------------------------------------------------------------
__global__ __launch_bounds__(64, 1) void rnn_main(
    const float* __restrict__ x, const float* __restrict__ hidden,
    const float* __restrict__ cost, const _Float16* __restrict__ WTP,
    const _Float16* __restrict__ woP, float* __restrict__ outs,
    float* __restrict__ hfin)
{
    __shared__ float costS[136];          // 128 + pad (OOB-safe prefetch)

    const int t = threadIdx.x;
    const int c = t & 15, g = t >> 4;
    const int b  = blockIdx.x >> 6;
    const int r0 = (blockIdx.x & 63) << 4;

    // ---- weights into registers: A-frag lane (c,g) = W[m=it*16+c][kb*32+g*8+u] ----
    h8 af[8][5];
#pragma unroll
    for (int it = 0; it < 8; ++it)
#pragma unroll
        for (int kb = 0; kb < 5; ++kb)
            af[it][kb] = *reinterpret_cast<const h8*>(
                &WTP[(it * 16 + c) * KP + kb * 32 + g * 8]);
    h8 wof[5];
#pragma unroll
    for (int kb = 0; kb < 5; ++kb)
        wof[kb] = *reinterpret_cast<const h8*>(&woP[kb * 32 + g * 8]);

    // ---- per-block cost table (keeps SMEM out of the loop) ----
    costS[t]      = cost[b * S_ + t];
    costS[t + 64] = cost[b * S_ + t + 64];
    if (t < 8) costS[128 + t] = 0.f;

    // ---- h(0) -> bf in B-frag layout: lane (c,g) = inter[row c][kb*32+g*8+u] ----
    h8 bf[4];
    {
        const float* hp = hidden + ((long)(b * R_ + r0 + c)) * H_;
#pragma unroll
        for (int kb = 0; kb < 4; ++kb) {
            float4 v0 = *reinterpret_cast<const float4*>(hp + kb * 32 + g * 8);
            float4 v1 = *reinterpret_cast<const float4*>(hp + kb * 32 + g * 8 + 4);
            bf[kb] = mk8(h2u(pk2(v0.x, v0.y)), h2u(pk2(v0.z, v0.w)),
                         h2u(pk2(v1.x, v1.y)), h2u(pk2(v1.z, v1.w)));
        }
    }

    // ---- x pipeline: lane (c,g) loads its own B-frag slice, 4-step distance ----
    const int xoff  = (g == 3) ? 21 : g * 8;     // g=3 reads x[21..24] (use .w)
    const int xoff2 = (g == 3) ? 0 : 4;
    const float* xlane = x + (((long)b * S_) * R_ + r0 + c) * KIN + xoff;

    float4 X0a, X0b, X1a, X1b, X2a, X2b, X3a, X3b;
    auto xinit = [&](int s, float4& v0, float4& v1) {
        const float* p = xlane + (long)s * (R_ * KIN);
        v0 = *reinterpret_cast<const float4*>(p);
        v1 = *reinterpret_cast<const float4*>(p + xoff2);
    };
    xinit(0, X0a, X0b); xinit(1, X1a, X1b); xinit(2, X2a, X2b); xinit(3, X3a, X3b);

    auto mkbx = [&](float4 v0, float4 v1, float cs) -> h8 {
        h2 z{};
        h2 d0 = (g == 3) ? pk2(v0.w, cs) : pk2(v0.x, v0.y);
        h2 d1 = (g == 3) ? z : pk2(v0.z, v0.w);
        h2 d2 = (g == 3) ? z : pk2(v1.x, v1.y);
        h2 d3 = (g == 3) ? z : pk2(v1.z, v1.w);
        return mk8(h2u(d0), h2u(d1), h2u(d2), h2u(d3));
    };

    const f4v fz = {0.f, 0.f, 0.f, 0.f};
    f4v acc[8];
    float4 ccA = *reinterpret_cast<const float4*>(&costS[0]);
    float4 ccB;

// one step: x-slab MFMAs first (only need bx), then h-slabs (need bf).
// Tail (pk2+permlane -> bf) of step s overlaps step s+1's x-slab issue.
#define STEP(SV, XV0, XV1, CSV, OG) do {                                        \
    h8 bx = mkbx(XV0, XV1, CSV);                                                \
    if ((SV) + 4 < S_) {                                                        \
        const float* p_ = xlane + (long)((SV) + 4) * (R_ * KIN);                \
        XV0 = *reinterpret_cast<const float4*>(p_);                             \
        XV1 = *reinterpret_cast<const float4*>(p_ + xoff2);                     \
    }                                                                           \
    _Pragma("unroll")                                                           \
    for (int it = 0; it < 8; ++it)                                              \
        acc[it] = __builtin_amdgcn_mfma_f32_16x16x32_f16(af[it][4], bx, fz, 0, 0, 0); \
    h2 po0 = __builtin_shufflevector(bx, bx, 0, 1) * __builtin_shufflevector(wof[4], wof[4], 0, 1); \
    h2 po1 = __builtin_shufflevector(bx, bx, 2, 3) * __builtin_shufflevector(wof[4], wof[4], 2, 3); \
    h2 po2 = __builtin_shufflevector(bx, bx, 4, 5) * __builtin_shufflevector(wof[4], wof[4], 4, 5); \
    h2 po3 = __builtin_shufflevector(bx, bx, 6, 7) * __builtin_shufflevector(wof[4], wof[4], 6, 7); \
    _Pragma("unroll")                                                           \
    for (int kb = 0; kb < 4; ++kb) {                                            \
        h8 bv = bf[kb];                                                         \
        _Pragma("unroll")                                                       \
        for (int it = 0; it < 8; ++it)                                          \
            acc[it] = __builtin_amdgcn_mfma_f32_16x16x32_f16(                   \
                af[it][kb], bv, acc[it], 0, 0, 0);                              \
        po0 += __builtin_shufflevector(bv, bv, 0, 1) * __builtin_shufflevector(wof[kb], wof[kb], 0, 1); \
        po1 += __builtin_shufflevector(bv, bv, 2, 3) * __builtin_shufflevector(wof[kb], wof[kb], 2, 3); \
        po2 += __builtin_shufflevector(bv, bv, 4, 5) * __builtin_shufflevector(wof[kb], wof[kb], 4, 5); \
        po3 += __builtin_shufflevector(bv, bv, 6, 7) * __builtin_shufflevector(wof[kb], wof[kb], 6, 7); \
    }                                                                           \
    { h2 pa = po0 + po1, pb = po2 + po3, pc = pa + pb;                          \
      OG = (float)pc[0] + (float)pc[1]; }                                       \
    if ((SV) < S_ - 1) {                                                        \
        _Pragma("unroll")                                                       \
        for (int kb = 0; kb < 4; ++kb) {                                        \
            unsigned A0 = h2u(pk2(acc[2*kb][0],   acc[2*kb][1]));               \
            unsigned A1 = h2u(pk2(acc[2*kb][2],   acc[2*kb][3]));               \
            unsigned B0 = h2u(pk2(acc[2*kb+1][0], acc[2*kb+1][1]));             \
            unsigned B1 = h2u(pk2(acc[2*kb+1][2], acc[2*kb+1][3]));             \
            auto r0_ = __builtin_amdgcn_permlane32_swap(A0, B0, false, false);  \
            auto q0_ = __builtin_amdgcn_permlane16_swap(r0_[0], r0_[1], false, false); \
            auto r1_ = __builtin_amdgcn_permlane32_swap(A1, B1, false, false);  \
            auto q1_ = __builtin_amdgcn_permlane16_swap(r1_[0], r1_[1], false, false); \
            bf[kb] = mk8(q0_[0], q1_[0], q0_[1], q1_[1]);                       \
        }                                                                       \
    }                                                                           \
} while (0)

// reduce 4 step-partials over g-groups (batched -> bpermute latency amortized)
#define OGFLUSH(S4, O0, O1, O2, O3) do {                                        \
    O0 += __shfl_xor(O0, 16, 64);  O1 += __shfl_xor(O1, 16, 64);                \
    O2 += __shfl_xor(O2, 16, 64);  O3 += __shfl_xor(O3, 16, 64);                \
    O0 += __shfl_xor(O0, 32, 64);  O1 += __shfl_xor(O1, 32, 64);                \
    O2 += __shfl_xor(O2, 32, 64);  O3 += __shfl_xor(O3, 32, 64);                \
    if (g == 0) {                                                               \
        float* op = outs + (long)(b * S_ + (S4)) * R_ + r0 + c;                 \
        op[0] = O0; op[R_] = O1; op[2 * R_] = O2; op[3 * R_] = O3;              \
    }                                                                           \
} while (0)

    for (int s4 = 0; s4 < S_; s4 += 8) {
        float og0, og1, og2, og3;
        ccB = *reinterpret_cast<const float4*>(&costS[s4 + 4]);
        STEP(s4 + 0, X0a, X0b, ccA[0], og0);
        STEP(s4 + 1, X1a, X1b, ccA[1], og1);
        STEP(s4 + 2, X2a, X2b, ccA[2], og2);
        STEP(s4 + 3, X3a, X3b, ccA[3], og3);
        OGFLUSH(s4, og0, og1, og2, og3);
        ccA = *reinterpret_cast<const float4*>(&costS[s4 + 8]);   // pad-safe
        STEP(s4 + 4, X0a, X0b, ccB[0], og0);
        STEP(s4 + 5, X1a, X1b, ccB[1], og1);
        STEP(s4 + 6, X2a, X2b, ccB[2], og2);
        STEP(s4 + 7, X3a, X3b, ccB[3], og3);
        OGFLUSH(s4 + 4, og0, og1, og2, og3);
    }
#undef STEP
#undef OGFLUSH

    // ---- h_final from step-127 accumulators (fp32, D layout i = it*16+g*4+j) ----
#pragma unroll
    for (int it = 0; it < 8; ++it)
        *reinterpret_cast<f4v*>(
            &hfin[((long)(b * R_ + r0 + c)) * H_ + it * 16 + g * 4]) = acc[it];
}

// ---------------------------------------------------------------------------
extern "C" void kernel_launch(void* const* d_in, const int* in_sizes, int n_in,
                              void* d_out, int out_size, void* d_ws, size_t ws_size,
                              hipStream_t stream)
{
    const float* x      = (const float*)d_in[0];
    const float* hidden = (const float*)d_in[1];
    const float* cost   = (const float*)d_in[2];
    const float* Wo1    = (const float*)d_in[3];
    const float* Wo2    = (const float*)d_in[4];
    const float* Wh1    = (const float*)d_in[5];
    const float* Wh2    = (const float*)d_in[6];

    float* outs = (float*)d_out;                    // [B,S,R]
    float* hfin = outs + (long)B_ * S_ * R_;        // [B,R,H]

    _Float16* WTP = (_Float16*)d_ws;                // [128][160]
    _Float16* woP = WTP + (size_t)H_ * KP;          // [160]

    prep_kernel<<<KP + 1, 128, 0, stream>>>(Wo1, Wo2, Wh1, Wh2, WTP, woP);
    rnn_main<<<1024, 64, 0, stream>>>(x, hidden, cost, WTP, woP, outs, hfin);
}

// Round 12
// 90.710 us; speedup vs baseline: 1.1047x; 1.1047x over previous
//
#include <hip/hip_runtime.h>

#define B_   16
#define S_   128
#define R_   1024
#define KIN  25
#define H_   128
#define MID  256
#define KP   160     // weight K stride (5 slabs of 32)

typedef _Float16 h8 __attribute__((ext_vector_type(8)));
typedef _Float16 h2 __attribute__((ext_vector_type(2)));
typedef float    f4v __attribute__((ext_vector_type(4)));

__device__ __forceinline__ h2 pk2(float a, float b) {
    auto r = __builtin_amdgcn_cvt_pkrtz(a, b);
    h2 o; o[0] = (_Float16)r[0]; o[1] = (_Float16)r[1]; return o;
}
__device__ __forceinline__ unsigned h2u(h2 v) {
    union { h2 h; unsigned u; } c; c.h = v; return c.u;
}
__device__ __forceinline__ h8 mk8(unsigned a, unsigned b, unsigned c, unsigned d) {
    union { h8 v; unsigned u[4]; } r; r.u[0] = a; r.u[1] = b; r.u[2] = c; r.u[3] = d;
    return r.v;
}

// inter k-order: [h(0..127) | x(128..152) | c(153) | pad(154..159)]
__device__ __forceinline__ int orig_k(int kp) {
    if (kp < H_)        return KIN + kp;
    if (kp < H_ + KIN)  return kp - H_;
    if (kp == H_ + KIN) return H_ + KIN;
    return -1;
}

// ---------------------------------------------------------------------------
__global__ void prep_kernel(const float* __restrict__ Wo1, const float* __restrict__ Wo2,
                            const float* __restrict__ Wh1, const float* __restrict__ Wh2,
                            _Float16* __restrict__ WTP, _Float16* __restrict__ woP)
{
    const int kp = blockIdx.x;
    const int t  = threadIdx.x;            // 128 threads
    if (kp < KP) {
        const int ok = orig_k(kp);
        float acc = 0.f;
        if (ok >= 0) {
            const float* w1 = Wh1 + (long)ok * MID;
            for (int m = 0; m < MID; ++m)
                acc += w1[m] * Wh2[m * H_ + t];
        }
        WTP[t * KP + kp] = (_Float16)acc;
    } else {
#pragma unroll
        for (int r = 0; r < 2; ++r) {
            int k2 = t + r * 128;
            if (k2 < KP) {
                int ok = orig_k(k2);
                float acc = 0.f;
                if (ok >= 0)
                    for (int m = 0; m < MID; ++m)
                        acc += Wo1[ok * MID + m] * Wo2[m];
                woP[k2] = (_Float16)acc;
            }
        }
    }
}

// ---------------------------------------------------------------------------
// 1024 blocks x 64 thr (1 wave/SIMD, full chip). Wave owns a 16-row chain.
// Recurrence 100% in registers (MFMA D -> pk2 -> permlane32/16_swap -> B-frag).
// 45 MFMAs/step (8 h-tiles + 1 out tile). x-slab (kb=4) issued FIRST so the
// previous step's pk2/permlane tail overlaps its issue. out = acco[0]
// broadcast (no shuffles). No LDS/SMEM/barriers in the loop.
// ---------------------------------------------------------------------------
__global__ __launch_bounds__(64, 1) void rnn_main(
    const float* __restrict__ x, const float* __restrict__ hidden,
    const float* __restrict__ cost, const _Float16* __restrict__ WTP,
    const _Float16* __restrict__ woP, float* __restrict__ outs,
    float* __restrict__ hfin)
{
    __shared__ float costS[136];          // 128 + pad (OOB-safe prefetch)

    const int t = threadIdx.x;
    const int c = t & 15, g = t >> 4;
    const int b  = blockIdx.x >> 6;
    const int r0 = (blockIdx.x & 63) << 4;

    // ---- weights into registers: A-frag lane (c,g) = W[m=it*16+c][kb*32+g*8+u] ----
    h8 af[8][5];
#pragma unroll
    for (int it = 0; it < 8; ++it)
#pragma unroll
        for (int kb = 0; kb < 5; ++kb)
            af[it][kb] = *reinterpret_cast<const h8*>(
                &WTP[(it * 16 + c) * KP + kb * 32 + g * 8]);
    h8 wz;
#pragma unroll
    for (int u = 0; u < 8; ++u) wz[u] = (_Float16)0.f;
    h8 afo[5];                            // out tile: A row 0 = wo, rest 0
#pragma unroll
    for (int kb = 0; kb < 5; ++kb) {
        h8 w = *reinterpret_cast<const h8*>(&woP[kb * 32 + g * 8]);
        afo[kb] = (c == 0) ? w : wz;
    }

    // ---- per-block cost table (keeps SMEM out of the loop) ----
    costS[t]      = cost[b * S_ + t];
    costS[t + 64] = cost[b * S_ + t + 64];
    if (t < 8) costS[128 + t] = 0.f;

    // ---- h(0) -> bf in B-frag layout: lane (c,g) = inter[row c][kb*32+g*8+u] ----
    h8 bf[4];
    {
        const float* hp = hidden + ((long)(b * R_ + r0 + c)) * H_;
#pragma unroll
        for (int kb = 0; kb < 4; ++kb) {
            float4 v0 = *reinterpret_cast<const float4*>(hp + kb * 32 + g * 8);
            float4 v1 = *reinterpret_cast<const float4*>(hp + kb * 32 + g * 8 + 4);
            bf[kb] = mk8(h2u(pk2(v0.x, v0.y)), h2u(pk2(v0.z, v0.w)),
                         h2u(pk2(v1.x, v1.y)), h2u(pk2(v1.z, v1.w)));
        }
    }

    // ---- x pipeline: lane (c,g) loads its own B-frag slice, 4-step distance ----
    const int xoff  = (g == 3) ? 21 : g * 8;     // g=3 reads x[21..24] (use .w)
    const int xoff2 = (g == 3) ? 0 : 4;
    const float* xlane = x + (((long)b * S_) * R_ + r0 + c) * KIN + xoff;

    float4 X0a, X0b, X1a, X1b, X2a, X2b, X3a, X3b;
    auto xinit = [&](int s, float4& v0, float4& v1) {
        const float* p = xlane + (long)s * (R_ * KIN);
        v0 = *reinterpret_cast<const float4*>(p);
        v1 = *reinterpret_cast<const float4*>(p + xoff2);
    };
    xinit(0, X0a, X0b); xinit(1, X1a, X1b); xinit(2, X2a, X2b); xinit(3, X3a, X3b);

    auto mkbx = [&](float4 v0, float4 v1, float cs) -> h8 {
        h2 z{};
        h2 d0 = (g == 3) ? pk2(v0.w, cs) : pk2(v0.x, v0.y);
        h2 d1 = (g == 3) ? z : pk2(v0.z, v0.w);
        h2 d2 = (g == 3) ? z : pk2(v1.x, v1.y);
        h2 d3 = (g == 3) ? z : pk2(v1.z, v1.w);
        return mk8(h2u(d0), h2u(d1), h2u(d2), h2u(d3));
    };

    const f4v fz = {0.f, 0.f, 0.f, 0.f};
    f4v acc[8], acco = fz;
    float4 ccA = *reinterpret_cast<const float4*>(&costS[0]);
    float4 ccB;

// one step: x-slab (kb=4) FIRST — depends only on bx, so the previous step's
// pk2/permlane tail overlaps its issue. Then h-slabs kb=0..3 (need bf).
// kb=3 runs it=0,1 first so the tail's bf[0] pair can start early.
#define STEP(SV, XV0, XV1, CSV, OG) do {                                        \
    h8 bx = mkbx(XV0, XV1, CSV);                                                \
    if ((SV) + 4 < S_) {                                                        \
        const float* p_ = xlane + (long)((SV) + 4) * (R_ * KIN);                \
        XV0 = *reinterpret_cast<const float4*>(p_);                             \
        XV1 = *reinterpret_cast<const float4*>(p_ + xoff2);                     \
    }                                                                           \
    _Pragma("unroll")                                                           \
    for (int it = 0; it < 8; ++it)                                              \
        acc[it] = __builtin_amdgcn_mfma_f32_16x16x32_f16(af[it][4], bx, fz, 0, 0, 0); \
    acco = __builtin_amdgcn_mfma_f32_16x16x32_f16(afo[4], bx, fz, 0, 0, 0);     \
    _Pragma("unroll")                                                           \
    for (int kb = 0; kb < 4; ++kb) {                                            \
        h8 bv = bf[kb];                                                         \
        _Pragma("unroll")                                                       \
        for (int it = 0; it < 8; ++it)                                          \
            acc[it] = __builtin_amdgcn_mfma_f32_16x16x32_f16(                   \
                af[it][kb], bv, acc[it], 0, 0, 0);                              \
        acco = __builtin_amdgcn_mfma_f32_16x16x32_f16(afo[kb], bv, acco, 0, 0, 0); \
    }                                                                           \
    OG = acco[0];                       /* D row 0 lives in g==0 lanes, reg 0 */\
    if ((SV) < S_ - 1) {                                                        \
        _Pragma("unroll")                                                       \
        for (int kb = 0; kb < 4; ++kb) {                                        \
            unsigned A0 = h2u(pk2(acc[2*kb][0],   acc[2*kb][1]));               \
            unsigned A1 = h2u(pk2(acc[2*kb][2],   acc[2*kb][3]));               \
            unsigned B0 = h2u(pk2(acc[2*kb+1][0], acc[2*kb+1][1]));             \
            unsigned B1 = h2u(pk2(acc[2*kb+1][2], acc[2*kb+1][3]));             \
            auto r0_ = __builtin_amdgcn_permlane32_swap(A0, B0, false, false);  \
            auto q0_ = __builtin_amdgcn_permlane16_swap(r0_[0], r0_[1], false, false); \
            auto r1_ = __builtin_amdgcn_permlane32_swap(A1, B1, false, false);  \
            auto q1_ = __builtin_amdgcn_permlane16_swap(r1_[0], r1_[1], false, false); \
            bf[kb] = mk8(q0_[0], q1_[0], q0_[1], q1_[1]);                       \
        }                                                                       \
    }                                                                           \
} while (0)

    for (int s4 = 0; s4 < S_; s4 += 8) {
        float og0, og1, og2, og3;
        ccB = *reinterpret_cast<const float4*>(&costS[s4 + 4]);
        STEP(s4 + 0, X0a, X0b, ccA[0], og0);
        STEP(s4 + 1, X1a, X1b, ccA[1], og1);
        STEP(s4 + 2, X2a, X2b, ccA[2], og2);
        STEP(s4 + 3, X3a, X3b, ccA[3], og3);
        if (g == 0) {
            float* op = outs + (long)(b * S_ + s4) * R_ + r0 + c;
            op[0] = og0; op[R_] = og1; op[2 * R_] = og2; op[3 * R_] = og3;
        }
        ccA = *reinterpret_cast<const float4*>(&costS[s4 + 8]);   // pad-safe
        STEP(s4 + 4, X0a, X0b, ccB[0], og0);
        STEP(s4 + 5, X1a, X1b, ccB[1], og1);
        STEP(s4 + 6, X2a, X2b, ccB[2], og2);
        STEP(s4 + 7, X3a, X3b, ccB[3], og3);
        if (g == 0) {
            float* op = outs + (long)(b * S_ + s4 + 4) * R_ + r0 + c;
            op[0] = og0; op[R_] = og1; op[2 * R_] = og2; op[3 * R_] = og3;
        }
    }
#undef STEP

    // ---- h_final from step-127 accumulators (fp32, D layout i = it*16+g*4+j) ----
#pragma unroll
    for (int it = 0; it < 8; ++it)
        *reinterpret_cast<f4v*>(
            &hfin[((long)(b * R_ + r0 + c)) * H_ + it * 16 + g * 4]) = acc[it];
}

// ---------------------------------------------------------------------------
extern "C" void kernel_launch(void* const* d_in, const int* in_sizes, int n_in,
                              void* d_out, int out_size, void* d_ws, size_t ws_size,
                              hipStream_t stream)
{
    const float* x      = (const float*)d_in[0];
    const float* hidden = (const float*)d_in[1];
    const float* cost   = (const float*)d_in[2];
    const float* Wo1    = (const float*)d_in[3];
    const float* Wo2    = (const float*)d_in[4];
    const float* Wh1    = (const float*)d_in[5];
    const float* Wh2    = (const float*)d_in[6];

    float* outs = (float*)d_out;                    // [B,S,R]
    float* hfin = outs + (long)B_ * S_ * R_;        // [B,R,H]

    _Float16* WTP = (_Float16*)d_ws;                // [128][160]
    _Float16* woP = WTP + (size_t)H_ * KP;          // [160]

    prep_kernel<<<KP + 1, 128, 0, stream>>>(Wo1, Wo2, Wh1, Wh2, WTP, woP);
    rnn_main<<<1024, 64, 0, stream>>>(x, hidden, cost, WTP, woP, outs, hfin);
}